// Round 4
// baseline (145.272 us; speedup 1.0000x reference)
//
#include <hip/hip_runtime.h>

typedef _Float16 f16x8 __attribute__((ext_vector_type(8)));
typedef _Float16 f16x4 __attribute__((ext_vector_type(4)));
typedef float    f32x4 __attribute__((ext_vector_type(4)));

#define MFMA16(A, B, C) __builtin_amdgcn_mfma_f32_16x16x32_f16((A), (B), (C), 0, 0, 0)

constexpr int Bsz = 4096, Ssz = 200, INsz = 8, Hsz = 128, OUTsz = 8, Psz = 50;
constexpr int ROWS = 16;   // batch rows per block
// d_ws layout (floats): G[128*128] @0 ; Go[8*128] @16384 ; d[128] @17408 ; co[8] @17536
constexpr int WS_G = 0, WS_GO = 16384, WS_D = 17408, WS_CO = 17536;

// ---------------- prologue: fold weight products ----------------
// G = W1@W2 (128x128), Go = Wout@W2 (8x128), d = W1@b2 (128), co = Wout@b2 (8)
__global__ void precomp_kernel(const float* __restrict__ W1, const float* __restrict__ W2,
                               const float* __restrict__ b2, const float* __restrict__ Wout,
                               float* __restrict__ ws) {
  int tid = (int)blockIdx.x * 256 + (int)threadIdx.x;
  if (tid < 16384) {                       // G[j][k]
    int j = tid >> 7, k = tid & 127;
    float acc = 0.f;
    #pragma unroll 8
    for (int m = 0; m < 128; ++m) acc = fmaf(W1[j*128 + m], W2[m*128 + k], acc);
    ws[WS_G + tid] = acc;
  } else if (tid < 16384 + 1024) {         // Go[o][k]
    int t = tid - 16384; int o = t >> 7, k = t & 127;
    float acc = 0.f;
    #pragma unroll 8
    for (int m = 0; m < 128; ++m) acc = fmaf(Wout[o*128 + m], W2[m*128 + k], acc);
    ws[WS_GO + t] = acc;
  } else if (tid < 16384 + 1024 + 128) {   // d[j] = sum_m b2[m]*W1[j][m]
    int j = tid - 17408;
    float acc = 0.f;
    for (int m = 0; m < 128; ++m) acc = fmaf(b2[m], W1[j*128 + m], acc);
    ws[WS_D + j] = acc;
  } else if (tid < 16384 + 1024 + 128 + 8) { // co[o] = sum_m b2[m]*Wout[o][m]
    int o = tid - 17536;
    float acc = 0.f;
    for (int m = 0; m < 128; ++m) acc = fmaf(b2[m], Wout[o*128 + m], acc);
    ws[WS_CO + o] = acc;
  }
}

// split fp32 x8 into fp16 hi + fp16 residual (register-resident weight frags)
#define SPLIT8(PTR, HI, LO) do { \
    const f32x4 va_ = *(const f32x4*)(PTR); \
    const f32x4 vb_ = *(const f32x4*)((PTR) + 4); \
    _Pragma("unroll") \
    for (int j_ = 0; j_ < 4; ++j_) { \
      _Float16 h0_ = (_Float16)va_[j_]; \
      (HI)[j_]     = h0_; \
      (LO)[j_]     = (_Float16)(va_[j_] - (float)h0_); \
      _Float16 h1_ = (_Float16)vb_[j_]; \
      (HI)[j_ + 4] = h1_; \
      (LO)[j_ + 4] = (_Float16)(vb_[j_] - (float)h1_); \
    } \
  } while (0)

// MFMA half-phase over this wave's two k-slots (ks0, ks0+1); 3-product hi/lo
// split, partial accumulated in fp32; helpers publish partial to pbuf[c].
#define MPHASE(AH, AL, SH, SL, BIAS, P) do { \
    const f16x8 u0h_ = *(const f16x8*)(&(SH)[((ks0+0)*64 + l)*8]); \
    const f16x8 u0l_ = *(const f16x8*)(&(SL)[((ks0+0)*64 + l)*8]); \
    const f16x8 u1h_ = *(const f16x8*)(&(SH)[((ks0+1)*64 + l)*8]); \
    const f16x8 u1l_ = *(const f16x8*)(&(SL)[((ks0+1)*64 + l)*8]); \
    f32x4 c_ = (BIAS); \
    f32x4 e_ = {0.f,0.f,0.f,0.f}, f_ = {0.f,0.f,0.f,0.f}; \
    c_ = MFMA16((AH)[0], u0h_, c_); \
    e_ = MFMA16((AL)[0], u0h_, e_); \
    f_ = MFMA16((AH)[0], u0l_, f_); \
    c_ = MFMA16((AH)[1], u1h_, c_); \
    e_ = MFMA16((AL)[1], u1h_, e_); \
    f_ = MFMA16((AH)[1], u1l_, f_); \
    (P) = c_ + e_ + f_; \
    if (!owner) pbuf[c][l] = (P); \
  } while (0)

// Go half-matmul (helpers c<2 only): consumes frag slots 2c, 2c+1 of (SH,SL)
#define GOPHASE(SH, SL) do { \
    const int gb_ = 2*c; \
    const f16x8 v0h_ = *(const f16x8*)(&(SH)[((gb_+0)*64 + l)*8]); \
    const f16x8 v0l_ = *(const f16x8*)(&(SL)[((gb_+0)*64 + l)*8]); \
    const f16x8 v1h_ = *(const f16x8*)(&(SH)[((gb_+1)*64 + l)*8]); \
    const f16x8 v1l_ = *(const f16x8*)(&(SL)[((gb_+1)*64 + l)*8]); \
    f32x4 cg_ = {0.f,0.f,0.f,0.f}, eg_ = {0.f,0.f,0.f,0.f}, fg_ = {0.f,0.f,0.f,0.f}; \
    cg_ = MFMA16(goh[0], v0h_, cg_); \
    eg_ = MFMA16(gol[0], v0h_, eg_); \
    fg_ = MFMA16(goh[0], v0l_, fg_); \
    cg_ = MFMA16(goh[1], v1h_, cg_); \
    eg_ = MFMA16(gol[1], v1h_, eg_); \
    fg_ = MFMA16(goh[1], v1l_, fg_); \
    pbuf[8 + c][l] = cg_ + eg_ + fg_; \
  } while (0)

// owner lane writes its 4 chans (ch0+4g..+3 of batch row r) as hi/lo f16x4
#define WPK(DH, DL, V) do { \
    f16x4 wh_, wl_; \
    _Pragma("unroll") \
    for (int q_ = 0; q_ < 4; ++q_) { \
      _Float16 hh_ = (_Float16)(V)[q_]; \
      wh_[q_] = hh_; wl_[q_] = (_Float16)((V)[q_] - (float)hh_); \
    } \
    *(f16x4*)(&(DH)[wb0]) = wh_; \
    *(f16x4*)(&(DL)[wb0]) = wl_; \
  } while (0)

__device__ inline f32x4 tanh4(f32x4 z) {
  f32x4 o;
  #pragma unroll
  for (int q = 0; q < 4; ++q) {
    float zz = fminf(fmaxf(z[q], -15.f), 15.f);
    float e  = __builtin_amdgcn_exp2f(2.8853900817779268f * zz); // e^(2x)
    o[q] = (e - 1.f) * __builtin_amdgcn_rcpf(e + 1.f);
  }
  return o;
}

__global__ __launch_bounds__(1024) void node_rk4_kernel(
    const float* __restrict__ x,    const float* __restrict__ Win,
    const float* __restrict__ binp, const float* __restrict__ W1,
    const float* __restrict__ b1,   const float* __restrict__ Wout,
    const float* __restrict__ bout, const float* __restrict__ ws,
    float* __restrict__ out)
{
  // packed frag buffers: slot (ks,lane) holds 8 halves = chans [32ks+8*(l>>4)..+8) of row l&15
  __shared__ _Float16 bufA_hi[2048], bufA_lo[2048], bufB_hi[2048], bufB_lo[2048];
  __shared__ f32x4 pbuf[10][64];   // [0..7]: G-partials per chan-group; [8..9]: Go partials

  const int tid = (int)threadIdx.x;
  const int w   = tid >> 6;          // wave 0..15
  const int c   = w & 7;             // chan-group: chans [16c, 16c+16)
  const int h   = w >> 3;            // k-half: 0 = owner (k 0..63), 1 = helper (k 64..127)
  const bool owner = (h == 0);
  const int l   = tid & 63;
  const int g   = l >> 4;
  const int r   = l & 15;            // batch row within tile
  const int rowbase = (int)blockIdx.x * ROWS;
  const int ch0 = c * 16;
  const int ks0 = 2 * h;             // this wave's first k-slot
  // packed write slot for owner chans ch0+4g+q of row r
  const int wb0 = ((c >> 1)*512 + (2*(c & 1) + (g >> 1))*128 + r*8) + 4*(g & 1);
  const f32x4 zero = {0.f,0.f,0.f,0.f};

  // ---------- persistent weight fragments (own 2 k-slots only) ----------
  f16x8 Gh[2], Gl[2];
  #pragma unroll
  for (int ks = 0; ks < 2; ++ks)
    SPLIT8(ws + WS_G + (size_t)(ch0 + r)*Hsz + 32*(ks0 + ks) + 8*g, Gh[ks], Gl[ks]);

  f16x8 goh[2], gol[2];              // Go frags: helper waves c<2 (k-slots 2c, 2c+1)
  if (!owner && c < 2) {
    #pragma unroll
    for (int ks = 0; ks < 2; ++ks) {
      if (r < OUTsz) SPLIT8(ws + WS_GO + (size_t)r*Hsz + 32*(2*c + ks) + 8*g, goh[ks], gol[ks]);
      else {
        #pragma unroll
        for (int j = 0; j < 8; ++j) { goh[ks][j] = (_Float16)0.f; gol[ks][j] = (_Float16)0.f; }
      }
    }
  }

  // bias vectors (owner: real; helper: zero so partials carry no bias)
  const f32x4 dvw  = owner ? *(const f32x4*)(ws + WS_D + ch0 + 4*g) : zero;
  const f32x4 dv6w = 6.f * dvw;
  f32x4 cov6 = zero, boutv = zero;
  if (w == 0 && g < 2) {
    cov6  = 6.f * *(const f32x4*)(ws + WS_CO + 4*g);
    boutv = *(const f32x4*)(bout + 4*g);
  }

  // ---------- y0 = x[:, S-1, :] @ Win^T + bin (owners), staged to bufA ----------
  if (owner) {
    const float* xr = x + ((size_t)(rowbase + r)*Ssz + (Ssz - 1))*INsz;
    const f32x4 xa = *(const f32x4*)xr;
    const f32x4 xb = *(const f32x4*)(xr + 4);
    const f32x4 binv = *(const f32x4*)(binp + ch0 + 4*g);
    f32x4 yv;
    #pragma unroll
    for (int q = 0; q < 4; ++q) {
      const float* wrp = Win + (size_t)(ch0 + 4*g + q)*INsz;
      const f32x4 wa = *(const f32x4*)wrp;
      const f32x4 wb = *(const f32x4*)(wrp + 4);
      float acc = binv[q];
      #pragma unroll
      for (int i = 0; i < 4; ++i) acc += xa[i]*wa[i] + xb[i]*wb[i];
      yv[q] = acc;
    }
    WPK(bufA_hi, bufA_lo, yv);
  }
  __syncthreads();

  // ---------- init: z = y0@W1^T + b1 ; o = y0@Wout^T (via helpers) ----------
  f32x4 z, o, Ta, m, pA;
  {
    f16x8 a1h[2], a1l[2];
    #pragma unroll
    for (int ks = 0; ks < 2; ++ks)
      SPLIT8(W1 + (size_t)(ch0 + r)*Hsz + 32*(ks0 + ks) + 8*g, a1h[ks], a1l[ks]);
    const f32x4 b1w = owner ? *(const f32x4*)(b1 + ch0 + 4*g) : zero;
    MPHASE(a1h, a1l, bufA_hi, bufA_lo, b1w, pA);
    if (!owner && c < 2) {
      f16x8 woh[2], wol[2];
      #pragma unroll
      for (int ks = 0; ks < 2; ++ks) {
        if (r < OUTsz) SPLIT8(Wout + (size_t)r*Hsz + 32*(2*c + ks) + 8*g, woh[ks], wol[ks]);
        else {
          #pragma unroll
          for (int j = 0; j < 8; ++j) { woh[ks][j] = (_Float16)0.f; wol[ks][j] = (_Float16)0.f; }
        }
      }
      const int gb = 2*c;
      const f16x8 v0h = *(const f16x8*)(&bufA_hi[((gb+0)*64 + l)*8]);
      const f16x8 v0l = *(const f16x8*)(&bufA_lo[((gb+0)*64 + l)*8]);
      const f16x8 v1h = *(const f16x8*)(&bufA_hi[((gb+1)*64 + l)*8]);
      const f16x8 v1l = *(const f16x8*)(&bufA_lo[((gb+1)*64 + l)*8]);
      f32x4 cg = zero, eg = zero, fg = zero;
      cg = MFMA16(woh[0], v0h, cg); eg = MFMA16(wol[0], v0h, eg); fg = MFMA16(woh[0], v0l, fg);
      cg = MFMA16(woh[1], v1h, cg); eg = MFMA16(wol[1], v1h, eg); fg = MFMA16(woh[1], v1l, fg);
      pbuf[8 + c][l] = cg + eg + fg;
    }
    __syncthreads();
    if (owner) z = pA + pbuf[c][l];
    if (w == 0) o = pbuf[8][l] + pbuf[9][l];
  }

  // ---------- RK4 in z-space: 4 matmul-stages/step, owner/helper k-split ----------
  #pragma unroll 1
  for (int p = 0; p < Psz; ++p) {
    if (w == 0 && g < 2) {   // out_p = o + bout (chans 4g..4g+3 of row r)
      float* dst = out + ((size_t)(rowbase + r)*Psz + p)*OUTsz + 4*g;
      *(f32x4*)dst = o + boutv;
    }
    if (p == Psz - 1) break;

    // s1: t1 = tanh(z) -> bufA (owners only)
    if (owner) { f32x4 t = tanh4(z); Ta = t; WPK(bufA_hi, bufA_lo, t); }
    __syncthreads();                                        // F1

    // s2: m = t1@G^T + d ; t2 = tanh(z + 0.5m) -> bufB
    MPHASE(Gh, Gl, bufA_hi, bufA_lo, dvw, pA);
    __syncthreads();                                        // P2
    if (owner) { m = pA + pbuf[c][l]; f32x4 t = tanh4(z + 0.5f*m);
                 Ta += 2.f*t; WPK(bufB_hi, bufB_lo, t); }
    __syncthreads();                                        // F2

    // s3: m = t2@G^T + d ; t3 = tanh(z + 0.5m) -> bufA
    MPHASE(Gh, Gl, bufB_hi, bufB_lo, dvw, pA);
    __syncthreads();                                        // P3
    if (owner) { m = pA + pbuf[c][l]; f32x4 t = tanh4(z + 0.5f*m);
                 Ta += 2.f*t; WPK(bufA_hi, bufA_lo, t); }
    __syncthreads();                                        // F3

    // s4: m = t3@G^T + d ; t4 = tanh(z + m) ; T -> bufB
    MPHASE(Gh, Gl, bufA_hi, bufA_lo, dvw, pA);
    __syncthreads();                                        // P4
    if (owner) { m = pA + pbuf[c][l]; f32x4 t = tanh4(z + m);
                 Ta += t; WPK(bufB_hi, bufB_lo, Ta); }
    __syncthreads();                                        // F4

    // s5: z += (T@G^T + 6d)/6 ; o += (T@Go^T + 6co)/6 (Go via helpers c<2)
    MPHASE(Gh, Gl, bufB_hi, bufB_lo, dv6w, pA);
    if (!owner && c < 2) GOPHASE(bufB_hi, bufB_lo);
    __syncthreads();                                        // P5
    if (owner) { m = pA + pbuf[c][l]; z += (1.f/6.f)*m; }
    if (w == 0) o += (1.f/6.f)*(pbuf[8][l] + pbuf[9][l] + cov6);
    // no barrier: next s1 writes bufA (last read before P4); helpers' next
    // pbuf writes are after F1, by which owners' P5 reads have drained.
  }
}

extern "C" void kernel_launch(void* const* d_in, const int* in_sizes, int n_in,
                              void* d_out, int out_size, void* d_ws, size_t ws_size,
                              hipStream_t stream) {
  (void)in_sizes; (void)n_in; (void)ws_size; (void)out_size;
  const float* x    = (const float*)d_in[0];
  const float* Win  = (const float*)d_in[1];
  const float* binp = (const float*)d_in[2];
  const float* W1   = (const float*)d_in[3];
  const float* b1   = (const float*)d_in[4];
  const float* W2   = (const float*)d_in[5];
  const float* b2   = (const float*)d_in[6];
  const float* Wout = (const float*)d_in[7];
  const float* bout = (const float*)d_in[8];
  float* ws = (float*)d_ws;

  precomp_kernel<<<69, 256, 0, stream>>>(W1, W2, b2, Wout, ws);
  node_rk4_kernel<<<Bsz / ROWS, 1024, 0, stream>>>(x, Win, binp, W1, b1, Wout,
                                                   bout, ws, (float*)d_out);
}